// Round 5
// baseline (227.782 us; speedup 1.0000x reference)
//
#include <hip/hip_runtime.h>
#include <math.h>

#define H    64
#define N    256
#define D    128
#define L    16
#define SEG4   112                 // float4 per 448-col segment
#define F3IN (N * 448)             // 114688 floats per W1 row
#define ROWS_PB 8                  // rows per k_mv block
#define CGS   16                   // column groups (16 segments each)
#define NBLK  ((512 / ROWS_PB) * CGS)   // 1024

typedef float v4f __attribute__((ext_vector_type(4)));

__device__ __forceinline__ float sigmoidf_(float x) {
    return 1.0f / (1.0f + expf(-x));
}
__device__ __forceinline__ float dot4(float4 a, float4 b) {
    return a.x * b.x + a.y * b.y + a.z * b.z + a.w * b.w;
}

// ---------------------------------------------------------------------------
// Kernel 1: encoder. emb gather + gi hoist + GRU(16 steps, 2 barriers each) +
// f1W transform (column preloaded to regs early) + u,v + paired-tree factored
// softmax. Z_ij = u_i + v_j + const; const cancels in the flat softmax.
// Outputs: g[64], eus[256] (= eu/(Su*Sv)), ev[256]. Also zeroes the epilogue
// counter for k_mv.
// ---------------------------------------------------------------------------
__global__ __launch_bounds__(256, 1) void k_enc(
    const int* __restrict__ token_ids, const float* __restrict__ emb_table,
    const float* __restrict__ Wih, const float* __restrict__ Whh,
    const float* __restrict__ bih, const float* __restrict__ bhh,
    const float* __restrict__ f1W, const float* __restrict__ obs,
    float* __restrict__ g_out, float* __restrict__ eus_out,
    float* __restrict__ ev_out, unsigned int* __restrict__ counter)
{
    __shared__ float emb_s[L * H];      // [16][64]
    __shared__ float gi_all[L * 192];   // [16][192]
    __shared__ float h_s[H];
    __shared__ float gh_s[192];
    __shared__ float wa_s[D];
    __shared__ float wb_s[D];
    __shared__ float red[256];
    __shared__ float red2[256];

    const int k = threadIdx.x;
    if (k == 0) *counter = 0u;

    // emb gather: 1 float4 per thread
    {
        int tok = token_ids[k >> 4];
        ((float4*)emb_s)[k] = ((const float4*)emb_table)[tok * 16 + (k & 15)];
    }
    if (k < H) h_s[k] = 0.0f;

    // gate-row register cache (threads 0..191)
    float4 wih4[16], whh4[16];
    float bi = 0.0f, bh = 0.0f;
    if (k < 192) {
        const float4* wi = (const float4*)(Wih + k * H);
        const float4* wh = (const float4*)(Whh + k * H);
#pragma unroll
        for (int c = 0; c < 16; ++c) { wih4[c] = wi[c]; whh4[c] = wh[c]; }
        bi = bih[k]; bh = bhh[k];
    }

    // f1W column k preloaded early; consumed after the GRU (latency hidden)
    float f1wreg[64];
#pragma unroll
    for (int kk = 0; kk < 64; ++kk) f1wreg[kk] = f1W[kk * 256 + k];

    __syncthreads();

    // hoist all input-gate terms: gi_all[t][k] = bih[k] + Wih[k,:].emb[t]
    if (k < 192) {
        float gi[L];
#pragma unroll
        for (int tt = 0; tt < L; ++tt) gi[tt] = bi;
#pragma unroll
        for (int c = 0; c < 16; ++c) {
            float4 w = wih4[c];
#pragma unroll
            for (int tt = 0; tt < L; ++tt)
                gi[tt] += dot4(w, ((const float4*)(emb_s + tt * 64))[c]);
        }
#pragma unroll
        for (int tt = 0; tt < L; ++tt) gi_all[tt * 192 + k] = gi[tt];
    }
    __syncthreads();

    // serial GRU, 2 barriers per step
    for (int tt = 0; tt < L; ++tt) {
        if (k < 192) {
            const float4* hv = (const float4*)h_s;
            float a0 = 0, a1 = 0, a2 = 0, a3 = 0;
#pragma unroll
            for (int c = 0; c < 16; c += 4) {
                a0 += dot4(whh4[c],     hv[c]);
                a1 += dot4(whh4[c + 1], hv[c + 1]);
                a2 += dot4(whh4[c + 2], hv[c + 2]);
                a3 += dot4(whh4[c + 3], hv[c + 3]);
            }
            gh_s[k] = (a0 + a1) + (a2 + a3) + bh;
        }
        __syncthreads();
        if (k < H) {
            float r = sigmoidf_(gi_all[tt * 192 + k] + gh_s[k]);
            float z = sigmoidf_(gi_all[tt * 192 + 64 + k] + gh_s[64 + k]);
            float n = tanhf(gi_all[tt * 192 + 128 + k] + r * gh_s[128 + k]);
            h_s[k] = (1.0f - z) * n + z * h_s[k];
        }
        __syncthreads();
    }

    // wa/wb from preloaded f1W column
    {
        float s = 0.0f;
#pragma unroll
        for (int kk = 0; kk < 64; ++kk) s += f1wreg[kk] * h_s[kk];
        if (k < D) wa_s[k] = s;
        else       wb_s[k - D] = s;
        if (k < H) g_out[k] = h_s[k];
    }
    __syncthreads();

    // u_i, v_i (thread = row i); load-all-then-compute
    float4 orow[32];
    {
        const float4* rp = (const float4*)(obs + k * D);
#pragma unroll
        for (int c = 0; c < 32; ++c) orow[c] = rp[c];
    }
    float u = 0.0f, v = 0.0f;
#pragma unroll
    for (int c = 0; c < 32; ++c) {
        u += dot4(orow[c], ((const float4*)wa_s)[c]);
        v += dot4(orow[c], ((const float4*)wb_s)[c]);
    }

    // paired max trees
    red[k] = u; red2[k] = v; __syncthreads();
    for (int s = 128; s > 0; s >>= 1) {
        if (k < s) { red[k] = fmaxf(red[k], red[k + s]); red2[k] = fmaxf(red2[k], red2[k + s]); }
        __syncthreads();
    }
    const float mu = red[0], mv = red2[0];
    __syncthreads();
    const float eui = expf(u - mu), evi = expf(v - mv);
    red[k] = eui; red2[k] = evi; __syncthreads();
    for (int s = 128; s > 0; s >>= 1) {
        if (k < s) { red[k] += red[k + s]; red2[k] += red2[k + s]; }
        __syncthreads();
    }
    const float Su = red[0], Sv = red2[0];

    eus_out[k] = eui * (1.0f / (Su * Sv));
    ev_out[k]  = evi;
}

// ---------------------------------------------------------------------------
// Kernel 2: W1 matvec with virtual x + fused epilogue.
// Block (rg, cg) handles rows rg*8..rg*8+7 over column-group cg (16 segments
// = 1792 float4). x-slice built ONCE into 7 regs/thread; hot loop is pure
// {nontemporal load, 4 FMA} x 56. Partials in per-block exclusive 128B lines.
// Last block (device atomic counter) computes h1 + W2 matvec.
// ---------------------------------------------------------------------------
__global__ __launch_bounds__(256) void k_mv(
    const float* __restrict__ W1, const float* __restrict__ obs,
    const float* __restrict__ g, const float* __restrict__ eus,
    const float* __restrict__ ev, float* __restrict__ partial,
    const float* __restrict__ b1, const float* __restrict__ W2,
    const float* __restrict__ b2, float* __restrict__ out,
    unsigned int* __restrict__ counter)
{
    const int t  = threadIdx.x;
    const int cg = blockIdx.x & 15;
    const int rg = blockIdx.x >> 4;

    // ---- virtual-x slice for this column group (zone logic runs ONCE) ----
    v4f xr[7];
    {
        const float4* obs4 = (const float4*)obs;
        const float4* g4   = (const float4*)g;
        const float4* ev4  = (const float4*)ev;
#pragma unroll
        for (int j = 0; j < 7; ++j) {
            int idx = t + j * 256;           // < 1792
            int s   = idx / SEG4;
            int c   = idx - s * SEG4;
            int seg = cg * 16 + s;
            float4 o;
            if (c < 32)       o = obs4[seg * 32 + c];
            else if (c < 48)  o = g4[c - 32];
            else {
                float4 e = ev4[c - 48];
                float m = eus[seg];
                o = make_float4(e.x * m, e.y * m, e.z * m, e.w * m);
            }
            xr[j] = (v4f){o.x, o.y, o.z, o.w};
        }
    }

    // ---- stream 8 rows x 28 KiB contiguous each ----
    const v4f* wbase = (const v4f*)W1 + (size_t)(rg * ROWS_PB) * (F3IN / 4)
                     + (size_t)cg * 1792 + t;
    float sums[ROWS_PB];
#pragma unroll
    for (int rr = 0; rr < ROWS_PB; ++rr) {
        const v4f* w = wbase + (size_t)rr * (F3IN / 4);
        float a0 = 0.0f, a1 = 0.0f;
#pragma unroll
        for (int j = 0; j < 7; ++j) {
            v4f wv = __builtin_nontemporal_load(w + j * 256);
            float d = wv[0] * xr[j][0] + wv[1] * xr[j][1]
                    + wv[2] * xr[j][2] + wv[3] * xr[j][3];
            if (j & 1) a1 += d; else a0 += d;
        }
        sums[rr] = a0 + a1;
    }

    // ---- reductions after the stream ----
    __shared__ float red[ROWS_PB * 4];
    __shared__ unsigned int last_s;
    const int wave = t >> 6, lane = t & 63;
#pragma unroll
    for (int rr = 0; rr < ROWS_PB; ++rr) {
        float s = sums[rr];
#pragma unroll
        for (int off = 32; off > 0; off >>= 1) s += __shfl_down(s, off, 64);
        if (lane == 0) red[rr * 4 + wave] = s;
    }
    __syncthreads();
    if (t < ROWS_PB) {
        partial[blockIdx.x * 32 + t] =
            red[t * 4] + red[t * 4 + 1] + red[t * 4 + 2] + red[t * 4 + 3];
    }
    __threadfence();                      // release partials to device scope
    __syncthreads();
    if (t == 0) last_s = (atomicAdd(counter, 1u) == (NBLK - 1)) ? 1u : 0u;
    __syncthreads();
    if (!last_s) return;
    __threadfence();                      // acquire

    // ---- epilogue: h1 = relu(rowsum + b1); out = W2 @ h1 + b2 ----
    __shared__ float h1s[512];
    for (int r = t; r < 512; r += 256) {
        const int rgb = r >> 3, rr = r & 7;
        float s = 0.0f;
#pragma unroll
        for (int cgi = 0; cgi < CGS; ++cgi)
            s += partial[(rgb * CGS + cgi) * 32 + rr];
        h1s[r] = fmaxf(s + b1[r], 0.0f);
    }
    __syncthreads();
    for (int row = wave; row < 40; row += 4) {
        float s = 0.0f;
#pragma unroll
        for (int c = 0; c < 8; ++c)
            s += W2[row * 512 + lane + c * 64] * h1s[lane + c * 64];
#pragma unroll
        for (int off = 32; off > 0; off >>= 1) s += __shfl_down(s, off, 64);
        if (lane == 0) out[row] = s + b2[row];
    }
}

// ---------------------------------------------------------------------------
extern "C" void kernel_launch(void* const* d_in, const int* in_sizes, int n_in,
                              void* d_out, int out_size, void* d_ws, size_t ws_size,
                              hipStream_t stream)
{
    const float* obs       = (const float*)d_in[0];
    const int*   token_ids = (const int*)  d_in[1];
    const float* emb_table = (const float*)d_in[2];
    const float* Wih       = (const float*)d_in[3];
    const float* Whh       = (const float*)d_in[4];
    const float* bih       = (const float*)d_in[5];
    const float* bhh       = (const float*)d_in[6];
    const float* f1W       = (const float*)d_in[7];
    // d_in[8] = f1_b : cancels in the flat softmax (Z_ij = u_i + v_j + const)
    const float* W1        = (const float*)d_in[9];
    const float* b1        = (const float*)d_in[10];
    const float* W2        = (const float*)d_in[11];
    const float* b2        = (const float*)d_in[12];

    float* ws      = (float*)d_ws;
    float* g       = ws;            // 64
    float* eus     = ws + 64;       // 256
    float* ev      = ws + 320;      // 256
    unsigned int* counter = (unsigned int*)(ws + 576);  // 1 (own line)
    float* partial = ws + 640;      // 1024 blocks * 32 (128B exclusive each)
    float* out     = (float*)d_out;

    k_enc<<<1, 256, 0, stream>>>(token_ids, emb_table, Wih, Whh, bih, bhh,
                                 f1W, obs, g, eus, ev, counter);
    k_mv<<<NBLK, 256, 0, stream>>>(W1, obs, g, eus, ev, partial,
                                   b1, W2, b2, out, counter);
}

// Round 6
// 71.942 us; speedup vs baseline: 3.1662x; 3.1662x over previous
//
#include <hip/hip_runtime.h>
#include <math.h>

#define H    64
#define N    256
#define D    128
#define L    16
#define SEG4   112                 // float4 per 448-col segment
#define F3IN (N * 448)             // 114688 floats per W1 row
#define CG4   1792                 // float4 per column group (16 segments)

typedef float v4f __attribute__((ext_vector_type(4)));

__device__ __forceinline__ float sigmoidf_(float x) {
    return 1.0f / (1.0f + expf(-x));
}
__device__ __forceinline__ float dot4(float4 a, float4 b) {
    return a.x * b.x + a.y * b.y + a.z * b.z + a.w * b.w;
}
__device__ __forceinline__ float dotv(v4f a, v4f b) {
    return a[0] * b[0] + a[1] * b[1] + a[2] * b[2] + a[3] * b[3];
}

// ---------------------------------------------------------------------------
// Kernel 1: encoder. emb gather + gi hoist + GRU(16 steps, 2 barriers each) +
// f1W transform (column preloaded early) + factored flat softmax.
// Z_ij = u_i + v_j + const; const cancels. Outputs g[64], eus[256], ev[256].
// ---------------------------------------------------------------------------
__global__ __launch_bounds__(256, 1) void k_enc(
    const int* __restrict__ token_ids, const float* __restrict__ emb_table,
    const float* __restrict__ Wih, const float* __restrict__ Whh,
    const float* __restrict__ bih, const float* __restrict__ bhh,
    const float* __restrict__ f1W, const float* __restrict__ obs,
    float* __restrict__ g_out, float* __restrict__ eus_out,
    float* __restrict__ ev_out)
{
    __shared__ float emb_s[L * H];
    __shared__ float gi_all[L * 192];
    __shared__ float h_s[H];
    __shared__ float gh_s[192];
    __shared__ float wa_s[D];
    __shared__ float wb_s[D];
    __shared__ float red[256];
    __shared__ float red2[256];

    const int k = threadIdx.x;

    {
        int tok = token_ids[k >> 4];
        ((float4*)emb_s)[k] = ((const float4*)emb_table)[tok * 16 + (k & 15)];
    }
    if (k < H) h_s[k] = 0.0f;

    float4 wih4[16], whh4[16];
    float bi = 0.0f, bh = 0.0f;
    if (k < 192) {
        const float4* wi = (const float4*)(Wih + k * H);
        const float4* wh = (const float4*)(Whh + k * H);
#pragma unroll
        for (int c = 0; c < 16; ++c) { wih4[c] = wi[c]; whh4[c] = wh[c]; }
        bi = bih[k]; bh = bhh[k];
    }

    float f1wreg[64];
#pragma unroll
    for (int kk = 0; kk < 64; ++kk) f1wreg[kk] = f1W[kk * 256 + k];

    __syncthreads();

    if (k < 192) {
        float gi[L];
#pragma unroll
        for (int tt = 0; tt < L; ++tt) gi[tt] = bi;
#pragma unroll
        for (int c = 0; c < 16; ++c) {
            float4 w = wih4[c];
#pragma unroll
            for (int tt = 0; tt < L; ++tt)
                gi[tt] += dot4(w, ((const float4*)(emb_s + tt * 64))[c]);
        }
#pragma unroll
        for (int tt = 0; tt < L; ++tt) gi_all[tt * 192 + k] = gi[tt];
    }
    __syncthreads();

    for (int tt = 0; tt < L; ++tt) {
        if (k < 192) {
            const float4* hv = (const float4*)h_s;
            float a0 = 0, a1 = 0, a2 = 0, a3 = 0;
#pragma unroll
            for (int c = 0; c < 16; c += 4) {
                a0 += dot4(whh4[c],     hv[c]);
                a1 += dot4(whh4[c + 1], hv[c + 1]);
                a2 += dot4(whh4[c + 2], hv[c + 2]);
                a3 += dot4(whh4[c + 3], hv[c + 3]);
            }
            gh_s[k] = (a0 + a1) + (a2 + a3) + bh;
        }
        __syncthreads();
        if (k < H) {
            float r = sigmoidf_(gi_all[tt * 192 + k] + gh_s[k]);
            float z = sigmoidf_(gi_all[tt * 192 + 64 + k] + gh_s[64 + k]);
            float n = tanhf(gi_all[tt * 192 + 128 + k] + r * gh_s[128 + k]);
            h_s[k] = (1.0f - z) * n + z * h_s[k];
        }
        __syncthreads();
    }

    {
        float s = 0.0f;
#pragma unroll
        for (int kk = 0; kk < 64; ++kk) s += f1wreg[kk] * h_s[kk];
        if (k < D) wa_s[k] = s;
        else       wb_s[k - D] = s;
        if (k < H) g_out[k] = h_s[k];
    }
    __syncthreads();

    float4 orow[32];
    {
        const float4* rp = (const float4*)(obs + k * D);
#pragma unroll
        for (int c = 0; c < 32; ++c) orow[c] = rp[c];
    }
    float u = 0.0f, v = 0.0f;
#pragma unroll
    for (int c = 0; c < 32; ++c) {
        u += dot4(orow[c], ((const float4*)wa_s)[c]);
        v += dot4(orow[c], ((const float4*)wb_s)[c]);
    }

    red[k] = u; red2[k] = v; __syncthreads();
    for (int s = 128; s > 0; s >>= 1) {
        if (k < s) { red[k] = fmaxf(red[k], red[k + s]); red2[k] = fmaxf(red2[k], red2[k + s]); }
        __syncthreads();
    }
    const float mu = red[0], mv = red2[0];
    __syncthreads();
    const float eui = expf(u - mu), evi = expf(v - mv);
    red[k] = eui; red2[k] = evi; __syncthreads();
    for (int s = 128; s > 0; s >>= 1) {
        if (k < s) { red[k] += red[k + s]; red2[k] += red2[k + s]; }
        __syncthreads();
    }
    const float Su = red[0], Sv = red2[0];

    eus_out[k] = eui * (1.0f / (Su * Sv));
    ev_out[k]  = evi;
}

// ---------------------------------------------------------------------------
// Kernel 2: W1 matvec with virtual x. Block (rg, cg): rows {2rg, 2rg+1} over
// column-group cg (1792 float4 = 28 KiB contiguous per row). x-slice built
// once into 7 regs/thread; hot loop = 14 interleaved nontemporal loads + FMA.
// 4096 blocks, no atomics, no fences.
// ---------------------------------------------------------------------------
__global__ __launch_bounds__(256, 4) void k_mv(
    const float* __restrict__ W1, const float* __restrict__ obs,
    const float* __restrict__ g, const float* __restrict__ eus,
    const float* __restrict__ ev, float* __restrict__ partial)
{
    const int t  = threadIdx.x;
    const int cg = blockIdx.x & 15;
    const int rg = blockIdx.x >> 4;        // 0..255

    // virtual-x slice for this column group (zone logic runs once)
    v4f xr[7];
    {
        const float4* obs4 = (const float4*)obs;
        const float4* g4   = (const float4*)g;
        const float4* ev4  = (const float4*)ev;
#pragma unroll
        for (int j = 0; j < 7; ++j) {
            int idx = t + j * 256;           // < 1792
            int s   = idx / SEG4;
            int c   = idx - s * SEG4;
            int seg = cg * 16 + s;
            float4 o;
            if (c < 32)       o = obs4[seg * 32 + c];
            else if (c < 48)  o = g4[c - 32];
            else {
                float4 e = ev4[c - 48];
                float m = eus[seg];
                o = make_float4(e.x * m, e.y * m, e.z * m, e.w * m);
            }
            xr[j] = (v4f){o.x, o.y, o.z, o.w};
        }
    }

    // two rows, interleaved loads for deeper in-flight queue
    const v4f* w0 = (const v4f*)W1 + (size_t)(rg * 2) * (F3IN / 4)
                  + (size_t)cg * CG4 + t;
    const v4f* w1 = w0 + (F3IN / 4);

    float s0a = 0.0f, s0b = 0.0f, s1a = 0.0f, s1b = 0.0f;
#pragma unroll
    for (int j = 0; j < 7; ++j) {
        v4f wa = __builtin_nontemporal_load(w0 + j * 256);
        v4f wb = __builtin_nontemporal_load(w1 + j * 256);
        float da = dotv(wa, xr[j]);
        float db = dotv(wb, xr[j]);
        if (j & 1) { s0b += da; s1b += db; }
        else       { s0a += da; s1a += db; }
    }
    float sums[2] = { s0a + s0b, s1a + s1b };

    __shared__ float red[2][4];
    const int wave = t >> 6, lane = t & 63;
#pragma unroll
    for (int rr = 0; rr < 2; ++rr) {
        float s = sums[rr];
#pragma unroll
        for (int off = 32; off > 0; off >>= 1) s += __shfl_down(s, off, 64);
        if (lane == 0) red[rr][wave] = s;
    }
    __syncthreads();
    if (t < 2)
        partial[(rg * 2 + t) * 16 + cg] =
            red[t][0] + red[t][1] + red[t][2] + red[t][3];
}

// ---------------------------------------------------------------------------
// Kernel 3: h1 = relu(sum of 16 partials + b1); out = W2 @ h1 + b2. One block.
// ---------------------------------------------------------------------------
__global__ __launch_bounds__(512) void k_finish(
    const float* __restrict__ partial, const float* __restrict__ b1,
    const float* __restrict__ W2, const float* __restrict__ b2,
    float* __restrict__ out)
{
    __shared__ float h1s[512];
    const int r = threadIdx.x;
    {
        const float4* p4 = (const float4*)(partial + r * 16);
        float4 A = p4[0], B = p4[1], C = p4[2], E = p4[3];
        float s = (A.x + A.y + A.z + A.w) + (B.x + B.y + B.z + B.w)
                + (C.x + C.y + C.z + C.w) + (E.x + E.y + E.z + E.w);
        h1s[r] = fmaxf(s + b1[r], 0.0f);
    }
    __syncthreads();

    const int wave = r >> 6, lane = r & 63;
    for (int row = wave; row < 40; row += 8) {
        float s = 0.0f;
#pragma unroll
        for (int c = 0; c < 8; ++c)
            s += W2[row * 512 + lane + c * 64] * h1s[lane + c * 64];
#pragma unroll
        for (int off = 32; off > 0; off >>= 1) s += __shfl_down(s, off, 64);
        if (lane == 0) out[row] = s + b2[row];
    }
}

// ---------------------------------------------------------------------------
extern "C" void kernel_launch(void* const* d_in, const int* in_sizes, int n_in,
                              void* d_out, int out_size, void* d_ws, size_t ws_size,
                              hipStream_t stream)
{
    const float* obs       = (const float*)d_in[0];
    const int*   token_ids = (const int*)  d_in[1];
    const float* emb_table = (const float*)d_in[2];
    const float* Wih       = (const float*)d_in[3];
    const float* Whh       = (const float*)d_in[4];
    const float* bih       = (const float*)d_in[5];
    const float* bhh       = (const float*)d_in[6];
    const float* f1W       = (const float*)d_in[7];
    // d_in[8] = f1_b : cancels in the flat softmax (Z_ij = u_i + v_j + const)
    const float* W1        = (const float*)d_in[9];
    const float* b1        = (const float*)d_in[10];
    const float* W2        = (const float*)d_in[11];
    const float* b2        = (const float*)d_in[12];

    float* ws      = (float*)d_ws;
    float* g       = ws;            // 64
    float* eus     = ws + 64;       // 256
    float* ev      = ws + 320;      // 256
    float* partial = ws + 640;      // 512*16 = 8192
    float* out     = (float*)d_out;

    k_enc<<<1, 256, 0, stream>>>(token_ids, emb_table, Wih, Whh, bih, bhh,
                                 f1W, obs, g, eus, ev);
    k_mv<<<4096, 256, 0, stream>>>(W1, obs, g, eus, ev, partial);
    k_finish<<<1, 512, 0, stream>>>(partial, b1, W2, b2, out);
}